// Round 15
// baseline (217.643 us; speedup 1.0000x reference)
//
#include <hip/hip_runtime.h>
#include <math.h>

#define D 256
#define S 4096
#define H 8
#define DH 32
#define DM 1024
#define NTOK 8192   // B*S

typedef __attribute__((ext_vector_type(8))) short short8;
typedef __attribute__((ext_vector_type(4))) float f32x4;

// qscale = (1/sqrt(32)) * log2(e): folds softmax scale + exp->exp2 into Q
#define QSCALE (0.17677669529663687f * 1.4426950408889634f)

__device__ inline unsigned short f2bf(float f) {
    union { float f; unsigned u; } v; v.f = f;
    unsigned r = v.u + 0x7fffu + ((v.u >> 16) & 1u);
    return (unsigned short)(r >> 16);
}
__device__ inline void gload16(const void* g, void* l) {
    __builtin_amdgcn_global_load_lds((const __attribute__((address_space(1))) void*)g,
                                     (__attribute__((address_space(3))) void*)l, 16, 0, 0);
}

// -------- fp32 -> bf16 weights + RoPE cos/sin table, one launch --------
__global__ void conv_all(const float* __restrict__ Wq, const float* __restrict__ Wk,
                         const float* __restrict__ Wv, const float* __restrict__ Wo,
                         const float* __restrict__ W2, const float* __restrict__ W3,
                         unsigned short* __restrict__ wqkv, unsigned short* __restrict__ wo_b,
                         unsigned short* __restrict__ w2_b, unsigned short* __restrict__ w3_b,
                         float* __restrict__ ct, float* __restrict__ st) {
    int i = blockIdx.x * 256 + threadIdx.x;       // 0 .. 851967
    if (i < 196608) {
        const float* s = (i < 65536) ? Wq : ((i < 131072) ? Wk : Wv);
        wqkv[i] = f2bf(s[i & 65535]);
    } else if (i < 262144) {
        wo_b[i - 196608] = f2bf(Wo[i - 196608]);
    } else if (i < 524288) {
        w2_b[i - 262144] = f2bf(W2[i - 262144]);
    } else if (i < 786432) {
        w3_b[i - 524288] = f2bf(W3[i - 524288]);
    } else {
        int j = i - 786432;                        // 0 .. 65535
        int spos = j >> 4, pi = j & 15;
        float inv_freq = powf(10000.0f, -(float)(2 * pi) / 32.0f);
        float fr = (float)spos * inv_freq;
        ct[j] = cosf(fr);
        st[j] = sinf(fr);
    }
}

// ------- bf16 MFMA GEMM with FUSED LayerNorm on A, 64x64 tile, K=256 -------
// A-tile rows are complete rows of the fp32 activation (K=256=D): each wave
// LayerNorms its 16 rows (float4/lane, wave shuffle reduce) and writes bf16 into
// the swizzled A-LDS layout (phys chunk = c ^ (row&7); lane l -> chunk (l>>1)^(row&7),
// 16 lanes span all 32 banks). A resident for all 4 B-phases; B double-buffered.
// modes: 0 = QKV: RoPE+store bf16 for cols<512 (Q cols<256 pre-scaled), cols>=512
//            stored TRANSPOSED to vt[B][H][DH][S];  2 = bf16 store gelu(acc+bias)
__global__ __launch_bounds__(256) void gemm_ln(const float* __restrict__ Ax,
        const unsigned short* __restrict__ Bw, void* __restrict__ outp,
        unsigned short* __restrict__ vt, const float* __restrict__ bias,
        const float* __restrict__ lng, const float* __restrict__ lnb,
        const float* __restrict__ ct, const float* __restrict__ st,
        int N, int mode) {
    __shared__ unsigned short As[64 * 256];      // 32KB, single-buffered (LN output)
    __shared__ unsigned short Bs[2][64 * 64];    // 16KB, dbuf over 4 phases of BK=64
    int tid = threadIdx.x;
    int w = tid >> 6, l = tid & 63;
    int lm = l & 15, lg = l >> 4;
    int wm = (w >> 1) * 32, wn = (w & 1) * 32;
    int bm = blockIdx.x * 64, bn = blockIdx.y * 64;
    // B staging (BK=64): slot tid -> row tid>>3, chunk tid&7; global chunk = c^(row&7)
    int r1 = tid >> 3, pc = tid & 7;
    int pcx = (pc ^ (r1 & 7)) * 8;
    const unsigned short* Bg1 = Bw + (size_t)(bn + r1) * 256 + pcx;
    const unsigned short* Bg2 = Bw + (size_t)(bn + 32 + r1) * 256 + pcx;
    const int swz = lm & 7;
    f32x4 acc[2][2] = {};

    // phase-0 B prefetch flies under the LN compute below
    gload16(Bg1, &Bs[0][w * 512]);
    gload16(Bg2, &Bs[0][2048 + w * 512]);

    // ---- fused LayerNorm: wave w normalizes rows bm+w*16 .. +15 into As ----
    {
        const float4 gg = *(const float4*)(lng + l * 4);
        const float4 bb = *(const float4*)(lnb + l * 4);
        #pragma unroll 4
        for (int t = 0; t < 16; ++t) {
            const float4 v = *(const float4*)(Ax + (size_t)(bm + w * 16 + t) * 256 + l * 4);
            float s  = v.x + v.y + v.z + v.w;
            float s2 = v.x * v.x + v.y * v.y + v.z * v.z + v.w * v.w;
            #pragma unroll
            for (int off = 32; off > 0; off >>= 1) {
                s  += __shfl_xor(s, off, 64);
                s2 += __shfl_xor(s2, off, 64);
            }
            float mu  = s * (1.0f / D);
            float var = s2 * (1.0f / D) - mu * mu;
            float rs  = rsqrtf(var + 1e-5f);
            ushort4 o;
            o.x = f2bf((v.x - mu) * rs * gg.x + bb.x);
            o.y = f2bf((v.y - mu) * rs * gg.y + bb.y);
            o.z = f2bf((v.z - mu) * rs * gg.z + bb.z);
            o.w = f2bf((v.w - mu) * rs * gg.w + bb.w);
            *(ushort4*)&As[(w * 16 + t) * 256 + (((l >> 1) ^ (t & 7)) << 3) + (l & 1) * 4] = o;
        }
    }

    for (int p = 0; p < 4; ++p) {
        int cur = p & 1;
        __syncthreads();     // p=0: drains LN ds_writes + B0 prefetch; else dbuf ordering
        if (p < 3) {
            gload16(Bg1 + (p + 1) * 64, &Bs[1 - cur][w * 512]);
            gload16(Bg2 + (p + 1) * 64, &Bs[1 - cur][2048 + w * 512]);
        }
        #pragma unroll
        for (int j = 0; j < 2; ++j) {
            int cx = (j * 4 + lg) ^ swz;
            short8 af[2], bf[2];
            #pragma unroll
            for (int i = 0; i < 2; ++i)
                af[i] = *(const short8*)&As[(wm + i * 16 + lm) * 256 + p * 64 + cx * 8];
            #pragma unroll
            for (int i = 0; i < 2; ++i)
                bf[i] = *(const short8*)&Bs[cur][(wn + i * 16 + lm) * 64 + cx * 8];
            #pragma unroll
            for (int mi = 0; mi < 2; ++mi)
                #pragma unroll
                for (int ni = 0; ni < 2; ++ni)
                    acc[mi][ni] = __builtin_amdgcn_mfma_f32_16x16x32_bf16(af[mi], bf[ni], acc[mi][ni], 0, 0, 0);
        }
    }

    if (mode == 0) {
        if (bn >= 512) {
            // V part: store transposed to vt[B][H][DH][S]
            #pragma unroll
            for (int mi = 0; mi < 2; ++mi) {
                #pragma unroll
                for (int ni = 0; ni < 2; ++ni) {
                    int ng = bn + wn + ni * 16 + lm - 512;   // h*32+dh
                    int hh = ng >> 5, dh = ng & 31;
                    int mg0 = bm + wm + mi * 16 + lg * 4;
                    int bb = mg0 >> 12, ss = mg0 & 4095;
                    ushort4 pv;
                    pv.x = f2bf(acc[mi][ni][0]); pv.y = f2bf(acc[mi][ni][1]);
                    pv.z = f2bf(acc[mi][ni][2]); pv.w = f2bf(acc[mi][ni][3]);
                    *(ushort4*)(vt + ((size_t)((bb * 8 + hh) * 32 + dh)) * S + ss) = pv;
                }
            }
        } else {
            // RoPE on q/k columns (wave-uniform branch; shuffles are safe)
            #pragma unroll
            for (int mi = 0; mi < 2; ++mi) {
                #pragma unroll
                for (int ni = 0; ni < 2; ++ni) {
                    int ng = bn + wn + ni * 16 + lm;
                    int pi = (ng & 31) >> 1;
                    float sgn = (ng & 1) ? 1.f : -1.f;
                    float qs  = (ng < 256) ? QSCALE : 1.f;
                    #pragma unroll
                    for (int r2 = 0; r2 < 4; ++r2) {
                        int mg = bm + wm + mi * 16 + lg * 4 + r2;
                        int spos = mg & (S - 1);
                        float vv = acc[mi][ni][r2];
                        float pv = __shfl_xor(vv, 1, 64);
                        float cs = ct[spos * 16 + pi];
                        float sn = st[spos * 16 + pi];
                        float ov = (vv * cs + sgn * pv * sn) * qs;
                        ((unsigned short*)outp)[(size_t)mg * N + ng] = f2bf(ov);
                    }
                }
            }
        }
        return;
    }
    // mode 2: gelu(acc+bias), bf16 store
    #pragma unroll
    for (int mi = 0; mi < 2; ++mi) {
        #pragma unroll
        for (int ni = 0; ni < 2; ++ni) {
            int ng = bn + wn + ni * 16 + lm;
            #pragma unroll
            for (int r2 = 0; r2 < 4; ++r2) {
                int mg = bm + wm + mi * 16 + lg * 4 + r2;
                float t = acc[mi][ni][r2] + bias[ng];
                ((unsigned short*)outp)[(size_t)mg * N + ng] =
                    f2bf(0.5f * t * (1.0f + erff(t * 0.70710678118654752f)));
            }
        }
    }
}

// ------- bf16 MFMA GEMM, 32x64 tile, BK=128 dbuf: for the N=256 GEMMs -------
// modes: 1 = fp32 store acc+res; 3 = fp32 store acc+bias+res
__global__ __launch_bounds__(256) void gemm32(const unsigned short* __restrict__ A,
        const unsigned short* __restrict__ Bw, void* __restrict__ outp,
        const float* __restrict__ bias, const float* __restrict__ res,
        int N, int K, int mode) {
    __shared__ unsigned short As[2][32 * 128];
    __shared__ unsigned short Bs[2][64 * 128];
    int tid = threadIdx.x;
    int w = tid >> 6, l = tid & 63;
    int lm = l & 15, lg = l >> 4;
    int rm = (w >> 1) * 16, wn = (w & 1) * 32;
    int bm = blockIdx.x * 32, bn = blockIdx.y * 64;
    int r1 = tid >> 4, pc = tid & 15;
    int pcx = (pc ^ (r1 & 7)) * 8;
    const unsigned short* Ag1 = A + (size_t)(bm + r1) * K + pcx;        // rows 0..15
    const unsigned short* Ag2 = A + (size_t)(bm + 16 + r1) * K + pcx;   // rows 16..31
    const unsigned short* Bg1 = Bw + (size_t)(bn + r1) * K + pcx;
    const unsigned short* Bg2 = Bw + (size_t)(bn + 16 + r1) * K + pcx;
    const unsigned short* Bg3 = Bw + (size_t)(bn + 32 + r1) * K + pcx;
    const unsigned short* Bg4 = Bw + (size_t)(bn + 48 + r1) * K + pcx;
    const int swz = lm & 7;
    f32x4 acc[2] = {};

    gload16(Ag1, &As[0][w * 512]);
    gload16(Ag2, &As[0][2048 + w * 512]);
    gload16(Bg1, &Bs[0][w * 512]);
    gload16(Bg2, &Bs[0][2048 + w * 512]);
    gload16(Bg3, &Bs[0][4096 + w * 512]);
    gload16(Bg4, &Bs[0][6144 + w * 512]);
    for (int k0 = 0; k0 < K; k0 += 128) {
        int cur = (k0 >> 7) & 1;
        __syncthreads();
        if (k0 + 128 < K) {
            gload16(Ag1 + k0 + 128, &As[1 - cur][w * 512]);
            gload16(Ag2 + k0 + 128, &As[1 - cur][2048 + w * 512]);
            gload16(Bg1 + k0 + 128, &Bs[1 - cur][w * 512]);
            gload16(Bg2 + k0 + 128, &Bs[1 - cur][2048 + w * 512]);
            gload16(Bg3 + k0 + 128, &Bs[1 - cur][4096 + w * 512]);
            gload16(Bg4 + k0 + 128, &Bs[1 - cur][6144 + w * 512]);
        }
        #pragma unroll
        for (int j = 0; j < 4; ++j) {
            int ch = ((j * 4 + lg) ^ swz) * 8;
            short8 af = *(const short8*)&As[cur][(rm + lm) * 128 + ch];
            short8 bf[2];
            #pragma unroll
            for (int i = 0; i < 2; ++i) bf[i] = *(const short8*)&Bs[cur][(wn + i * 16 + lm) * 128 + ch];
            #pragma unroll
            for (int ni = 0; ni < 2; ++ni)
                acc[ni] = __builtin_amdgcn_mfma_f32_16x16x32_bf16(af, bf[ni], acc[ni], 0, 0, 0);
        }
    }

    #pragma unroll
    for (int ni = 0; ni < 2; ++ni) {
        int ng = bn + wn + ni * 16 + lm;
        #pragma unroll
        for (int r2 = 0; r2 < 4; ++r2) {
            int mg = bm + rm + lg * 4 + r2;
            float v = acc[ni][r2];
            size_t idx = (size_t)mg * N + ng;
            if (mode == 1) {
                ((float*)outp)[idx] = v + res[idx];
            } else {
                ((float*)outp)[idx] = v + bias[ng] + res[idx];
            }
        }
    }
}

// -------- MFMA flash attention: registers-only P, split-key dual groups (R12) ------
// XCD-clustered decode: bh = blockIdx.x & 15 -> blocks sharing one (b,h)'s K/V land
// on (mostly) the same XCD -> K/V L2-resident (verified: hbm_bytes -63% in R12).
__global__ __launch_bounds__(512) void attn_kernel(const unsigned short* __restrict__ Cq,
        const unsigned short* __restrict__ vt, unsigned short* __restrict__ out) {
    __shared__ unsigned short Ks[2][2][64][32];  // [grp][buf][phys key row][dim]
    __shared__ unsigned short Vs[2][2][32][64];  // [grp][buf][dim][key]
    __shared__ unsigned short Ones[16][64];      // row 0 = 1.0bf16, rest 0
    int tid = threadIdx.x;
    int w = tid >> 6, l = tid & 63;
    int grp = w >> 2, ws = w & 3;
    int lm = l & 15, lg = l >> 4;
    int qt = blockIdx.x >> 4;                    // XCD-cluster swizzle
    int bh = blockIdx.x & 15;
    int bb = bh >> 3, h = bh & 7;
    int q0 = qt * 64 + ws * 16;

    if (tid < 256) {   // ones tile init (16x64 ushorts = 256 lanes x 4)
        unsigned short val = (tid < 16) ? (unsigned short)0x3F80 : (unsigned short)0;
        *(ushort4*)(&Ones[0][0] + tid * 4) = make_ushort4(val, val, val, val);
    }

    const short8 qf = *(const short8*)(Cq + ((size_t)(bb * S + q0 + lm)) * 768 + h * DH + lg * 8);
    int p = ws * 16 + (l >> 2);
    int krow = ((p >> 5) << 5) + (((p >> 2) & 3) << 3) + (((p >> 4) & 1) << 2) + (p & 3);
    const unsigned short* kg = Cq + ((size_t)(bb * S)) * 768 + 256 + h * 32
                               + (size_t)krow * 768 + ((l & 3) ^ ((l >> 3) & 3)) * 8;
    const unsigned short* vg = vt + ((size_t)(bh * 32 + ws * 8 + (l >> 3))) * S + ((l & 7) ^ (l >> 3)) * 8;
    const int kswz = (lm >> 1) & 3;
    const int vswz = lm & 7;

    f32x4 o0 = {0.f, 0.f, 0.f, 0.f}, o1 = {0.f, 0.f, 0.f, 0.f}, o2 = {0.f, 0.f, 0.f, 0.f};
    const f32x4 z = {0.f, 0.f, 0.f, 0.f};

    gload16(kg + (size_t)grp * 64 * 768, &Ks[grp][0][ws * 16][0]);
    gload16(vg + (size_t)grp * 64,       &Vs[grp][0][ws * 8][0]);

    #pragma unroll 2
    for (int it = 0; it < S / 128; ++it) {       // 32 iterations per group
        int cur = it & 1;
        __syncthreads();
        if (it + 1 < S / 128) {
            size_t t = (size_t)(2 * (it + 1) + grp);
            gload16(kg + t * 64 * 768, &Ks[grp][1 - cur][ws * 16][0]);
            gload16(vg + t * 64,       &Vs[grp][1 - cur][ws * 8][0]);
        }
        #pragma unroll
        for (int half = 0; half < 2; ++half) {
            short8 kf0 = *(const short8*)&Ks[grp][cur][half * 32 + lm][(lg ^ kswz) * 8];
            short8 kf1 = *(const short8*)&Ks[grp][cur][half * 32 + 16 + lm][(lg ^ kswz) * 8];
            f32x4 s0 = __builtin_amdgcn_mfma_f32_16x16x32_bf16(kf0, qf, z, 0, 0, 0);
            f32x4 s1 = __builtin_amdgcn_mfma_f32_16x16x32_bf16(kf1, qf, z, 0, 0, 0);
            unsigned u0[4], u1[4];
            #pragma unroll
            for (int i = 0; i < 4; ++i) {
                union { float f; unsigned u; } c0, c1;
                c0.f = __builtin_amdgcn_exp2f(s0[i]);
                c1.f = __builtin_amdgcn_exp2f(s1[i]);
                u0[i] = c0.u;   // truncate to bf16 (bias cancels num/denom)
                u1[i] = c1.u;
            }
            union { unsigned u[4]; short8 s; } pk;
            pk.u[0] = __builtin_amdgcn_perm(u0[1], u0[0], 0x07060302u);
            pk.u[1] = __builtin_amdgcn_perm(u0[3], u0[2], 0x07060302u);
            pk.u[2] = __builtin_amdgcn_perm(u1[1], u1[0], 0x07060302u);
            pk.u[3] = __builtin_amdgcn_perm(u1[3], u1[2], 0x07060302u);
            short8 pf = pk.s;   // B-operand fragment: keys 8lg..8lg+7, q=lm
            int vc = ((half * 4 + lg) ^ vswz) * 8;
            short8 va0 = *(const short8*)&Vs[grp][cur][lm][vc];
            short8 va1 = *(const short8*)&Vs[grp][cur][16 + lm][vc];
            short8 va2 = *(const short8*)&Ones[lm][vc];
            o0 = __builtin_amdgcn_mfma_f32_16x16x32_bf16(va0, pf, o0, 0, 0, 0);
            o1 = __builtin_amdgcn_mfma_f32_16x16x32_bf16(va1, pf, o1, 0, 0, 0);
            o2 = __builtin_amdgcn_mfma_f32_16x16x32_bf16(va2, pf, o2, 0, 0, 0);
        }
    }
    // cross-group combine via LDS aliased onto group1's dead staging buffers
    f32x4* Red0 = (f32x4*)&Ks[1][0][0][0];   // 4KB
    f32x4* Red1 = (f32x4*)&Vs[1][0][0][0];   // 4KB
    float* Den  = (float*)&Ones[0][0];       // 1KB
    __syncthreads();
    if (grp) {
        Red0[ws * 64 + l] = o0;
        Red1[ws * 64 + l] = o1;
        Den[ws * 64 + l]  = o2[0];
    }
    __syncthreads();
    if (!grp) {
        f32x4 a0 = Red0[ws * 64 + l];
        f32x4 a1 = Red1[ws * 64 + l];
        float dd = o2[0] + Den[ws * 64 + l];
        #pragma unroll
        for (int i = 0; i < 4; ++i) { o0[i] += a0[i]; o1[i] += a1[i]; }
        float lsum = __shfl(dd, lm, 64);
        float inv = 1.0f / lsum;
        ushort4 r0, r1;
        r0.x = f2bf(o0[0] * inv); r0.y = f2bf(o0[1] * inv);
        r0.z = f2bf(o0[2] * inv); r0.w = f2bf(o0[3] * inv);
        r1.x = f2bf(o1[0] * inv); r1.y = f2bf(o1[1] * inv);
        r1.z = f2bf(o1[2] * inv); r1.w = f2bf(o1[3] * inv);
        unsigned short* ob = out + ((size_t)(bb * S + q0 + lm)) * D + h * DH;
        *(ushort4*)(ob + lg * 4)      = r0;
        *(ushort4*)(ob + 16 + lg * 4) = r1;
    }
}

extern "C" void kernel_launch(void* const* d_in, const int* in_sizes, int n_in,
                              void* d_out, int out_size, void* d_ws, size_t ws_size,
                              hipStream_t stream) {
    const float* x     = (const float*)d_in[0];
    const float* Wq    = (const float*)d_in[1];
    const float* Wk    = (const float*)d_in[2];
    const float* Wv    = (const float*)d_in[3];
    const float* Wo    = (const float*)d_in[4];
    const float* ln1_g = (const float*)d_in[5];
    const float* ln1_b = (const float*)d_in[6];
    const float* ln2_g = (const float*)d_in[7];
    const float* ln2_b = (const float*)d_in[8];
    const float* W2    = (const float*)d_in[9];
    const float* b2    = (const float*)d_in[10];
    const float* W3    = (const float*)d_in[11];
    const float* b3    = (const float*)d_in[12];

    char* w8 = (char*)d_ws;
    unsigned short* wqkv = (unsigned short*)(w8);             // 196608 ush
    unsigned short* wo_b = (unsigned short*)(w8 + 393216);    // 65536
    unsigned short* w2_b = (unsigned short*)(w8 + 524288);    // 262144
    unsigned short* w3_b = (unsigned short*)(w8 + 1048576);   // 262144
    float*          ct   = (float*)(w8 + 1572864);            // 65536 f32
    float*          st   = (float*)(w8 + 1835008);            // 65536 f32
    unsigned short* Cq   = (unsigned short*)(w8 + 6291456);   // 6.29M ush (QKV out)
    unsigned short* hb   = Cq;                                // MLP hidden reuses (16MB)
    unsigned short* vtb  = (unsigned short*)(w8 + 23068672);  // 2M ush
    unsigned short* ab   = (unsigned short*)(w8 + 27262976);  // 2M ush
    float*          mlpin= (float*)(w8 + 31457280);           // 2M f32

    conv_all<<<3328, 256, 0, stream>>>(Wq, Wk, Wv, Wo, W2, W3, wqkv, wo_b, w2_b, w3_b, ct, st);
    gemm_ln<<<dim3(128, 12), 256, 0, stream>>>(x, wqkv, Cq, vtb, nullptr, ln1_g, ln1_b, ct, st, 768, 0);
    attn_kernel<<<1024, 512, 0, stream>>>(Cq, vtb, ab);
    gemm32<<<dim3(256, 4), 256, 0, stream>>>(ab, wo_b, mlpin, nullptr, x, 256, 256, 1);
    gemm_ln<<<dim3(128, 16), 256, 0, stream>>>(mlpin, w2_b, hb, nullptr, b2, ln2_g, ln2_b, nullptr, nullptr, 1024, 2);
    gemm32<<<dim3(256, 4), 256, 0, stream>>>(hb, w3_b, (float*)d_out, b3, mlpin, 256, 1024, 3);
}

// Round 16
// 198.994 us; speedup vs baseline: 1.0937x; 1.0937x over previous
//
#include <hip/hip_runtime.h>
#include <math.h>

#define D 256
#define S 4096
#define H 8
#define DH 32
#define DM 1024
#define NTOK 8192   // B*S

typedef __attribute__((ext_vector_type(8))) short short8;
typedef __attribute__((ext_vector_type(4))) float f32x4;

// qscale = (1/sqrt(32)) * log2(e): folds softmax scale + exp->exp2 into Q
#define QSCALE (0.17677669529663687f * 1.4426950408889634f)

__device__ inline unsigned short f2bf(float f) {
    union { float f; unsigned u; } v; v.f = f;
    unsigned r = v.u + 0x7fffu + ((v.u >> 16) & 1u);
    return (unsigned short)(r >> 16);
}
__device__ inline void gload16(const void* g, void* l) {
    __builtin_amdgcn_global_load_lds((const __attribute__((address_space(1))) void*)g,
                                     (__attribute__((address_space(3))) void*)l, 16, 0, 0);
}

// ---- prep: weights fp32->bf16 + RoPE table + LayerNorm1, ONE launch ----
// blocks 0..3327: conversion/table; blocks 3328..5375: LN1 (1 wave = 1 row).
__global__ void prep(const float* __restrict__ Wq, const float* __restrict__ Wk,
                     const float* __restrict__ Wv, const float* __restrict__ Wo,
                     const float* __restrict__ W2, const float* __restrict__ W3,
                     unsigned short* __restrict__ wqkv, unsigned short* __restrict__ wo_b,
                     unsigned short* __restrict__ w2_b, unsigned short* __restrict__ w3_b,
                     float* __restrict__ ct, float* __restrict__ st,
                     const float* __restrict__ x, const float* __restrict__ g,
                     const float* __restrict__ b, unsigned short* __restrict__ xn) {
    int blk = blockIdx.x;
    if (blk < 3328) {
        int i = blk * 256 + threadIdx.x;           // 0 .. 851967
        if (i < 196608) {
            const float* s = (i < 65536) ? Wq : ((i < 131072) ? Wk : Wv);
            wqkv[i] = f2bf(s[i & 65535]);
        } else if (i < 262144) {
            wo_b[i - 196608] = f2bf(Wo[i - 196608]);
        } else if (i < 524288) {
            w2_b[i - 262144] = f2bf(W2[i - 262144]);
        } else if (i < 786432) {
            w3_b[i - 524288] = f2bf(W3[i - 524288]);
        } else {
            int j = i - 786432;                     // 0 .. 65535
            int spos = j >> 4, pi = j & 15;
            float inv_freq = powf(10000.0f, -(float)(2 * pi) / 32.0f);
            float fr = (float)spos * inv_freq;
            ct[j] = cosf(fr);
            st[j] = sinf(fr);
        }
        return;
    }
    // LayerNorm1: 1 wave = 1 row, float4/lane, no LDS/barriers
    int l = threadIdx.x & 63;
    int row = (blk - 3328) * 4 + (threadIdx.x >> 6);
    const float4 v = *(const float4*)(x + (size_t)row * D + l * 4);
    float s  = v.x + v.y + v.z + v.w;
    float s2 = v.x * v.x + v.y * v.y + v.z * v.z + v.w * v.w;
    #pragma unroll
    for (int off = 32; off > 0; off >>= 1) {
        s  += __shfl_xor(s, off, 64);
        s2 += __shfl_xor(s2, off, 64);
    }
    float mu  = s * (1.0f / D);
    float var = s2 * (1.0f / D) - mu * mu;
    float rs  = rsqrtf(var + 1e-5f);
    const float4 gg = *(const float4*)(g + l * 4);
    const float4 bb = *(const float4*)(b + l * 4);
    ushort4 o;
    o.x = f2bf((v.x - mu) * rs * gg.x + bb.x);
    o.y = f2bf((v.y - mu) * rs * gg.y + bb.y);
    o.z = f2bf((v.z - mu) * rs * gg.z + bb.z);
    o.w = f2bf((v.w - mu) * rs * gg.w + bb.w);
    *(ushort4*)(xn + (size_t)row * D + l * 4) = o;
}

// ---------------- LayerNorm: 1 wave = 1 row, float4/lane (for LN2) ----------------
__global__ void ln_kernel(const float* __restrict__ x, const float* __restrict__ g,
                          const float* __restrict__ b, unsigned short* __restrict__ out) {
    int l = threadIdx.x & 63;
    int row = blockIdx.x * 4 + (threadIdx.x >> 6);
    const float4 v = *(const float4*)(x + (size_t)row * D + l * 4);
    float s  = v.x + v.y + v.z + v.w;
    float s2 = v.x * v.x + v.y * v.y + v.z * v.z + v.w * v.w;
    #pragma unroll
    for (int off = 32; off > 0; off >>= 1) {
        s  += __shfl_xor(s, off, 64);
        s2 += __shfl_xor(s2, off, 64);
    }
    float mu  = s * (1.0f / D);
    float var = s2 * (1.0f / D) - mu * mu;
    float rs  = rsqrtf(var + 1e-5f);
    const float4 gg = *(const float4*)(g + l * 4);
    const float4 bb = *(const float4*)(b + l * 4);
    ushort4 o;
    o.x = f2bf((v.x - mu) * rs * gg.x + bb.x);
    o.y = f2bf((v.y - mu) * rs * gg.y + bb.y);
    o.z = f2bf((v.z - mu) * rs * gg.z + bb.z);
    o.w = f2bf((v.w - mu) * rs * gg.w + bb.w);
    *(ushort4*)(out + (size_t)row * D + l * 4) = o;
}

// ------- bf16 MFMA GEMM, 64x64 tile, BK=64 dbuf (4 barriers @K=256), swizzled -------
// modes: 0 = QKV: RoPE+store bf16 for cols<512 (Q cols<256 pre-scaled), cols>=512
//            stored TRANSPOSED to vt[B][H][DH][S];  2 = bf16 store gelu(acc+bias)
__global__ __launch_bounds__(256) void gemm64b(const unsigned short* __restrict__ A,
        const unsigned short* __restrict__ Bw, void* __restrict__ outp,
        unsigned short* __restrict__ vt,
        const float* __restrict__ bias,
        const float* __restrict__ ct, const float* __restrict__ st,
        int N, int K, int mode) {
    __shared__ unsigned short As[2][64 * 64];
    __shared__ unsigned short Bs[2][64 * 64];
    int tid = threadIdx.x;
    int w = tid >> 6, l = tid & 63;
    int lm = l & 15, lg = l >> 4;
    int wm = (w >> 1) * 32, wn = (w & 1) * 32;
    int bm = blockIdx.x * 64, bn = blockIdx.y * 64;
    int r1 = tid >> 3, pc = tid & 7;
    int pcx = (pc ^ (r1 & 7)) * 8;
    const unsigned short* Ag1 = A + (size_t)(bm + r1) * K + pcx;
    const unsigned short* Ag2 = A + (size_t)(bm + 32 + r1) * K + pcx;
    const unsigned short* Bg1 = Bw + (size_t)(bn + r1) * K + pcx;
    const unsigned short* Bg2 = Bw + (size_t)(bn + 32 + r1) * K + pcx;
    const int swz = lm & 7;
    f32x4 acc[2][2] = {};

    gload16(Ag1, &As[0][w * 512]);
    gload16(Ag2, &As[0][2048 + w * 512]);
    gload16(Bg1, &Bs[0][w * 512]);
    gload16(Bg2, &Bs[0][2048 + w * 512]);
    for (int k0 = 0; k0 < K; k0 += 64) {
        int cur = (k0 >> 6) & 1;
        __syncthreads();
        if (k0 + 64 < K) {
            gload16(Ag1 + k0 + 64, &As[1 - cur][w * 512]);
            gload16(Ag2 + k0 + 64, &As[1 - cur][2048 + w * 512]);
            gload16(Bg1 + k0 + 64, &Bs[1 - cur][w * 512]);
            gload16(Bg2 + k0 + 64, &Bs[1 - cur][2048 + w * 512]);
        }
        #pragma unroll
        for (int j = 0; j < 2; ++j) {
            int ch = ((j * 4 + lg) ^ swz) * 8;
            short8 af[2], bf[2];
            #pragma unroll
            for (int i = 0; i < 2; ++i) af[i] = *(const short8*)&As[cur][(wm + i * 16 + lm) * 64 + ch];
            #pragma unroll
            for (int i = 0; i < 2; ++i) bf[i] = *(const short8*)&Bs[cur][(wn + i * 16 + lm) * 64 + ch];
            #pragma unroll
            for (int mi = 0; mi < 2; ++mi)
                #pragma unroll
                for (int ni = 0; ni < 2; ++ni)
                    acc[mi][ni] = __builtin_amdgcn_mfma_f32_16x16x32_bf16(af[mi], bf[ni], acc[mi][ni], 0, 0, 0);
        }
    }

    if (mode == 0) {
        if (bn >= 512) {
            #pragma unroll
            for (int mi = 0; mi < 2; ++mi) {
                #pragma unroll
                for (int ni = 0; ni < 2; ++ni) {
                    int ng = bn + wn + ni * 16 + lm - 512;   // h*32+dh
                    int hh = ng >> 5, dh = ng & 31;
                    int mg0 = bm + wm + mi * 16 + lg * 4;
                    int bb = mg0 >> 12, ss = mg0 & 4095;
                    ushort4 pv;
                    pv.x = f2bf(acc[mi][ni][0]); pv.y = f2bf(acc[mi][ni][1]);
                    pv.z = f2bf(acc[mi][ni][2]); pv.w = f2bf(acc[mi][ni][3]);
                    *(ushort4*)(vt + ((size_t)((bb * 8 + hh) * 32 + dh)) * S + ss) = pv;
                }
            }
        } else {
            #pragma unroll
            for (int mi = 0; mi < 2; ++mi) {
                #pragma unroll
                for (int ni = 0; ni < 2; ++ni) {
                    int ng = bn + wn + ni * 16 + lm;
                    int pi = (ng & 31) >> 1;
                    float sgn = (ng & 1) ? 1.f : -1.f;
                    float qs  = (ng < 256) ? QSCALE : 1.f;
                    #pragma unroll
                    for (int r2 = 0; r2 < 4; ++r2) {
                        int mg = bm + wm + mi * 16 + lg * 4 + r2;
                        int spos = mg & (S - 1);
                        float vv = acc[mi][ni][r2];
                        float pv = __shfl_xor(vv, 1, 64);
                        float cs = ct[spos * 16 + pi];
                        float sn = st[spos * 16 + pi];
                        float ov = (vv * cs + sgn * pv * sn) * qs;
                        ((unsigned short*)outp)[(size_t)mg * N + ng] = f2bf(ov);
                    }
                }
            }
        }
        return;
    }
    // mode 2: gelu(acc+bias), bf16 store
    #pragma unroll
    for (int mi = 0; mi < 2; ++mi) {
        #pragma unroll
        for (int ni = 0; ni < 2; ++ni) {
            int ng = bn + wn + ni * 16 + lm;
            #pragma unroll
            for (int r2 = 0; r2 < 4; ++r2) {
                int mg = bm + wm + mi * 16 + lg * 4 + r2;
                float t = acc[mi][ni][r2] + bias[ng];
                ((unsigned short*)outp)[(size_t)mg * N + ng] =
                    f2bf(0.5f * t * (1.0f + erff(t * 0.70710678118654752f)));
            }
        }
    }
}

// ------- bf16 MFMA GEMM, 32x64 tile, BK=128 dbuf: for the N=256 GEMMs -------
// modes: 1 = fp32 store acc+res; 3 = fp32 store acc+bias+res
__global__ __launch_bounds__(256) void gemm32(const unsigned short* __restrict__ A,
        const unsigned short* __restrict__ Bw, void* __restrict__ outp,
        const float* __restrict__ bias, const float* __restrict__ res,
        int N, int K, int mode) {
    __shared__ unsigned short As[2][32 * 128];
    __shared__ unsigned short Bs[2][64 * 128];
    int tid = threadIdx.x;
    int w = tid >> 6, l = tid & 63;
    int lm = l & 15, lg = l >> 4;
    int rm = (w >> 1) * 16, wn = (w & 1) * 32;
    int bm = blockIdx.x * 32, bn = blockIdx.y * 64;
    int r1 = tid >> 4, pc = tid & 15;
    int pcx = (pc ^ (r1 & 7)) * 8;
    const unsigned short* Ag1 = A + (size_t)(bm + r1) * K + pcx;
    const unsigned short* Ag2 = A + (size_t)(bm + 16 + r1) * K + pcx;
    const unsigned short* Bg1 = Bw + (size_t)(bn + r1) * K + pcx;
    const unsigned short* Bg2 = Bw + (size_t)(bn + 16 + r1) * K + pcx;
    const unsigned short* Bg3 = Bw + (size_t)(bn + 32 + r1) * K + pcx;
    const unsigned short* Bg4 = Bw + (size_t)(bn + 48 + r1) * K + pcx;
    const int swz = lm & 7;
    f32x4 acc[2] = {};

    gload16(Ag1, &As[0][w * 512]);
    gload16(Ag2, &As[0][2048 + w * 512]);
    gload16(Bg1, &Bs[0][w * 512]);
    gload16(Bg2, &Bs[0][2048 + w * 512]);
    gload16(Bg3, &Bs[0][4096 + w * 512]);
    gload16(Bg4, &Bs[0][6144 + w * 512]);
    for (int k0 = 0; k0 < K; k0 += 128) {
        int cur = (k0 >> 7) & 1;
        __syncthreads();
        if (k0 + 128 < K) {
            gload16(Ag1 + k0 + 128, &As[1 - cur][w * 512]);
            gload16(Ag2 + k0 + 128, &As[1 - cur][2048 + w * 512]);
            gload16(Bg1 + k0 + 128, &Bs[1 - cur][w * 512]);
            gload16(Bg2 + k0 + 128, &Bs[1 - cur][2048 + w * 512]);
            gload16(Bg3 + k0 + 128, &Bs[1 - cur][4096 + w * 512]);
            gload16(Bg4 + k0 + 128, &Bs[1 - cur][6144 + w * 512]);
        }
        #pragma unroll
        for (int j = 0; j < 4; ++j) {
            int ch = ((j * 4 + lg) ^ swz) * 8;
            short8 af = *(const short8*)&As[cur][(rm + lm) * 128 + ch];
            short8 bf[2];
            #pragma unroll
            for (int i = 0; i < 2; ++i) bf[i] = *(const short8*)&Bs[cur][(wn + i * 16 + lm) * 128 + ch];
            #pragma unroll
            for (int ni = 0; ni < 2; ++ni)
                acc[ni] = __builtin_amdgcn_mfma_f32_16x16x32_bf16(af, bf[ni], acc[ni], 0, 0, 0);
        }
    }

    #pragma unroll
    for (int ni = 0; ni < 2; ++ni) {
        int ng = bn + wn + ni * 16 + lm;
        #pragma unroll
        for (int r2 = 0; r2 < 4; ++r2) {
            int mg = bm + rm + lg * 4 + r2;
            float v = acc[ni][r2];
            size_t idx = (size_t)mg * N + ng;
            if (mode == 1) {
                ((float*)outp)[idx] = v + res[idx];
            } else {
                ((float*)outp)[idx] = v + bias[ng] + res[idx];
            }
        }
    }
}

// -------- MFMA flash attention: registers-only P, split-key dual groups ----------
// XCD-clustered decode (verified: hbm_bytes -63%). Denominator now accumulated in
// registers during the exp/pack loop (lane (lm,lg) holds scores of q=lm only) and
// reduced with two xor-shuffles — removes the ones-row MFMA + 2 LDS reads/iter.
__global__ __launch_bounds__(512) void attn_kernel(const unsigned short* __restrict__ Cq,
        const unsigned short* __restrict__ vt, unsigned short* __restrict__ out) {
    __shared__ unsigned short Ks[2][2][64][32];  // [grp][buf][phys key row][dim]
    __shared__ unsigned short Vs[2][2][32][64];  // [grp][buf][dim][key]
    int tid = threadIdx.x;
    int w = tid >> 6, l = tid & 63;
    int grp = w >> 2, ws = w & 3;
    int lm = l & 15, lg = l >> 4;
    int qt = blockIdx.x >> 4;                    // XCD-cluster swizzle
    int bh = blockIdx.x & 15;
    int bb = bh >> 3, h = bh & 7;
    int q0 = qt * 64 + ws * 16;

    const short8 qf = *(const short8*)(Cq + ((size_t)(bb * S + q0 + lm)) * 768 + h * DH + lg * 8);
    int p = ws * 16 + (l >> 2);
    int krow = ((p >> 5) << 5) + (((p >> 2) & 3) << 3) + (((p >> 4) & 1) << 2) + (p & 3);
    const unsigned short* kg = Cq + ((size_t)(bb * S)) * 768 + 256 + h * 32
                               + (size_t)krow * 768 + ((l & 3) ^ ((l >> 3) & 3)) * 8;
    const unsigned short* vg = vt + ((size_t)(bh * 32 + ws * 8 + (l >> 3))) * S + ((l & 7) ^ (l >> 3)) * 8;
    const int kswz = (lm >> 1) & 3;
    const int vswz = lm & 7;

    f32x4 o0 = {0.f, 0.f, 0.f, 0.f}, o1 = {0.f, 0.f, 0.f, 0.f};
    float lacc = 0.f;
    const f32x4 z = {0.f, 0.f, 0.f, 0.f};

    gload16(kg + (size_t)grp * 64 * 768, &Ks[grp][0][ws * 16][0]);
    gload16(vg + (size_t)grp * 64,       &Vs[grp][0][ws * 8][0]);

    #pragma unroll 2
    for (int it = 0; it < S / 128; ++it) {       // 32 iterations per group
        int cur = it & 1;
        __syncthreads();
        if (it + 1 < S / 128) {
            size_t t = (size_t)(2 * (it + 1) + grp);
            gload16(kg + t * 64 * 768, &Ks[grp][1 - cur][ws * 16][0]);
            gload16(vg + t * 64,       &Vs[grp][1 - cur][ws * 8][0]);
        }
        #pragma unroll
        for (int half = 0; half < 2; ++half) {
            short8 kf0 = *(const short8*)&Ks[grp][cur][half * 32 + lm][(lg ^ kswz) * 8];
            short8 kf1 = *(const short8*)&Ks[grp][cur][half * 32 + 16 + lm][(lg ^ kswz) * 8];
            f32x4 s0 = __builtin_amdgcn_mfma_f32_16x16x32_bf16(kf0, qf, z, 0, 0, 0);
            f32x4 s1 = __builtin_amdgcn_mfma_f32_16x16x32_bf16(kf1, qf, z, 0, 0, 0);
            // lane (lm,lg): scores of q=lm for keys 8lg..8lg+7
            unsigned u0[4], u1[4];
            #pragma unroll
            for (int i = 0; i < 4; ++i) {
                union { float f; unsigned u; } c0, c1;
                c0.f = __builtin_amdgcn_exp2f(s0[i]);
                c1.f = __builtin_amdgcn_exp2f(s1[i]);
                lacc += c0.f + c1.f;
                u0[i] = c0.u;   // truncate to bf16 for the PV operand
                u1[i] = c1.u;
            }
            union { unsigned u[4]; short8 s; } pk;
            pk.u[0] = __builtin_amdgcn_perm(u0[1], u0[0], 0x07060302u);
            pk.u[1] = __builtin_amdgcn_perm(u0[3], u0[2], 0x07060302u);
            pk.u[2] = __builtin_amdgcn_perm(u1[1], u1[0], 0x07060302u);
            pk.u[3] = __builtin_amdgcn_perm(u1[3], u1[2], 0x07060302u);
            short8 pf = pk.s;   // B-operand fragment: keys 8lg..8lg+7, q=lm
            int vc = ((half * 4 + lg) ^ vswz) * 8;
            short8 va0 = *(const short8*)&Vs[grp][cur][lm][vc];
            short8 va1 = *(const short8*)&Vs[grp][cur][16 + lm][vc];
            o0 = __builtin_amdgcn_mfma_f32_16x16x32_bf16(va0, pf, o0, 0, 0, 0);
            o1 = __builtin_amdgcn_mfma_f32_16x16x32_bf16(va1, pf, o1, 0, 0, 0);
        }
    }
    // cross-group combine via LDS aliased onto group1's dead staging buffers
    f32x4* Red0 = (f32x4*)&Ks[1][0][0][0];   // 4KB
    f32x4* Red1 = (f32x4*)&Vs[1][0][0][0];   // 4KB
    float* Den  = (float*)&Ks[1][1][0][0];   // 1KB (of 4KB)
    __syncthreads();
    if (grp) {
        Red0[ws * 64 + l] = o0;
        Red1[ws * 64 + l] = o1;
        Den[ws * 64 + l]  = lacc;
    }
    __syncthreads();
    if (!grp) {
        f32x4 a0 = Red0[ws * 64 + l];
        f32x4 a1 = Red1[ws * 64 + l];
        float dd = lacc + Den[ws * 64 + l];
        dd += __shfl_xor(dd, 16, 64);
        dd += __shfl_xor(dd, 32, 64);
        #pragma unroll
        for (int i = 0; i < 4; ++i) { o0[i] += a0[i]; o1[i] += a1[i]; }
        float inv = 1.0f / dd;
        ushort4 r0, r1;
        r0.x = f2bf(o0[0] * inv); r0.y = f2bf(o0[1] * inv);
        r0.z = f2bf(o0[2] * inv); r0.w = f2bf(o0[3] * inv);
        r1.x = f2bf(o1[0] * inv); r1.y = f2bf(o1[1] * inv);
        r1.z = f2bf(o1[2] * inv); r1.w = f2bf(o1[3] * inv);
        unsigned short* ob = out + ((size_t)(bb * S + q0 + lm)) * D + h * DH;
        *(ushort4*)(ob + lg * 4)      = r0;
        *(ushort4*)(ob + 16 + lg * 4) = r1;
    }
}

extern "C" void kernel_launch(void* const* d_in, const int* in_sizes, int n_in,
                              void* d_out, int out_size, void* d_ws, size_t ws_size,
                              hipStream_t stream) {
    const float* x     = (const float*)d_in[0];
    const float* Wq    = (const float*)d_in[1];
    const float* Wk    = (const float*)d_in[2];
    const float* Wv    = (const float*)d_in[3];
    const float* Wo    = (const float*)d_in[4];
    const float* ln1_g = (const float*)d_in[5];
    const float* ln1_b = (const float*)d_in[6];
    const float* ln2_g = (const float*)d_in[7];
    const float* ln2_b = (const float*)d_in[8];
    const float* W2    = (const float*)d_in[9];
    const float* b2    = (const float*)d_in[10];
    const float* W3    = (const float*)d_in[11];
    const float* b3    = (const float*)d_in[12];

    char* w8 = (char*)d_ws;
    unsigned short* wqkv = (unsigned short*)(w8);             // 196608 ush
    unsigned short* wo_b = (unsigned short*)(w8 + 393216);    // 65536
    unsigned short* w2_b = (unsigned short*)(w8 + 524288);    // 262144
    unsigned short* w3_b = (unsigned short*)(w8 + 1048576);   // 262144
    float*          ct   = (float*)(w8 + 1572864);            // 65536 f32
    float*          st   = (float*)(w8 + 1835008);            // 65536 f32
    unsigned short* xn   = (unsigned short*)(w8 + 2097152);   // 2M ush (reused as yn)
    unsigned short* Cq   = (unsigned short*)(w8 + 6291456);   // 6.29M ush (QKV out)
    unsigned short* hb   = Cq;                                // MLP hidden reuses (16MB)
    unsigned short* vtb  = (unsigned short*)(w8 + 23068672);  // 2M ush
    unsigned short* ab   = (unsigned short*)(w8 + 27262976);  // 2M ush
    float*          mlpin= (float*)(w8 + 31457280);           // 2M f32
    unsigned short* yn   = xn;

    prep<<<5376, 256, 0, stream>>>(Wq, Wk, Wv, Wo, W2, W3, wqkv, wo_b, w2_b, w3_b,
                                   ct, st, x, ln1_g, ln1_b, xn);
    gemm64b<<<dim3(128, 12), 256, 0, stream>>>(xn, wqkv, Cq, vtb, nullptr, ct, st, 768, 256, 0);
    attn_kernel<<<1024, 512, 0, stream>>>(Cq, vtb, ab);
    gemm32<<<dim3(256, 4), 256, 0, stream>>>(ab, wo_b, mlpin, nullptr, x, 256, 256, 1);
    ln_kernel<<<NTOK / 4, 256, 0, stream>>>(mlpin, ln2_g, ln2_b, yn);
    gemm64b<<<dim3(128, 16), 256, 0, stream>>>(yn, w2_b, hb, nullptr, b2, nullptr, nullptr, 1024, 256, 2);
    gemm32<<<dim3(256, 4), 256, 0, stream>>>(hb, w3_b, (float*)d_out, b3, mlpin, 256, 1024, 3);
}

// Round 17
// 195.513 us; speedup vs baseline: 1.1132x; 1.0178x over previous
//
#include <hip/hip_runtime.h>
#include <math.h>

#define D 256
#define S 4096
#define H 8
#define DH 32
#define DM 1024
#define NTOK 8192   // B*S

typedef __attribute__((ext_vector_type(8))) short short8;
typedef __attribute__((ext_vector_type(4))) float f32x4;

// qscale = (1/sqrt(32)) * log2(e): folds softmax scale + exp->exp2 into Q
#define QSCALE (0.17677669529663687f * 1.4426950408889634f)

__device__ inline unsigned short f2bf(float f) {
    union { float f; unsigned u; } v; v.f = f;
    unsigned r = v.u + 0x7fffu + ((v.u >> 16) & 1u);
    return (unsigned short)(r >> 16);
}
__device__ inline void gload16(const void* g, void* l) {
    __builtin_amdgcn_global_load_lds((const __attribute__((address_space(1))) void*)g,
                                     (__attribute__((address_space(3))) void*)l, 16, 0, 0);
}

// ---- prep: weights fp32->bf16 + RoPE table + LayerNorm1, ONE launch ----
// blocks 0..3327: conversion/table; blocks 3328..5375: LN1 (1 wave = 1 row).
__global__ void prep(const float* __restrict__ Wq, const float* __restrict__ Wk,
                     const float* __restrict__ Wv, const float* __restrict__ Wo,
                     const float* __restrict__ W2, const float* __restrict__ W3,
                     unsigned short* __restrict__ wqkv, unsigned short* __restrict__ wo_b,
                     unsigned short* __restrict__ w2_b, unsigned short* __restrict__ w3_b,
                     float* __restrict__ ct, float* __restrict__ st,
                     const float* __restrict__ x, const float* __restrict__ g,
                     const float* __restrict__ b, unsigned short* __restrict__ xn) {
    int blk = blockIdx.x;
    if (blk < 3328) {
        int i = blk * 256 + threadIdx.x;           // 0 .. 851967
        if (i < 196608) {
            const float* s = (i < 65536) ? Wq : ((i < 131072) ? Wk : Wv);
            wqkv[i] = f2bf(s[i & 65535]);
        } else if (i < 262144) {
            wo_b[i - 196608] = f2bf(Wo[i - 196608]);
        } else if (i < 524288) {
            w2_b[i - 262144] = f2bf(W2[i - 262144]);
        } else if (i < 786432) {
            w3_b[i - 524288] = f2bf(W3[i - 524288]);
        } else {
            int j = i - 786432;                     // 0 .. 65535
            int spos = j >> 4, pi = j & 15;
            float inv_freq = powf(10000.0f, -(float)(2 * pi) / 32.0f);
            float fr = (float)spos * inv_freq;
            ct[j] = cosf(fr);
            st[j] = sinf(fr);
        }
        return;
    }
    // LayerNorm1: 1 wave = 1 row, float4/lane, no LDS/barriers
    int l = threadIdx.x & 63;
    int row = (blk - 3328) * 4 + (threadIdx.x >> 6);
    const float4 v = *(const float4*)(x + (size_t)row * D + l * 4);
    float s  = v.x + v.y + v.z + v.w;
    float s2 = v.x * v.x + v.y * v.y + v.z * v.z + v.w * v.w;
    #pragma unroll
    for (int off = 32; off > 0; off >>= 1) {
        s  += __shfl_xor(s, off, 64);
        s2 += __shfl_xor(s2, off, 64);
    }
    float mu  = s * (1.0f / D);
    float var = s2 * (1.0f / D) - mu * mu;
    float rs  = rsqrtf(var + 1e-5f);
    const float4 gg = *(const float4*)(g + l * 4);
    const float4 bb = *(const float4*)(b + l * 4);
    ushort4 o;
    o.x = f2bf((v.x - mu) * rs * gg.x + bb.x);
    o.y = f2bf((v.y - mu) * rs * gg.y + bb.y);
    o.z = f2bf((v.z - mu) * rs * gg.z + bb.z);
    o.w = f2bf((v.w - mu) * rs * gg.w + bb.w);
    *(ushort4*)(xn + (size_t)row * D + l * 4) = o;
}

// ---------------- LayerNorm: 1 wave = 1 row, float4/lane (for LN2) ----------------
__global__ void ln_kernel(const float* __restrict__ x, const float* __restrict__ g,
                          const float* __restrict__ b, unsigned short* __restrict__ out) {
    int l = threadIdx.x & 63;
    int row = blockIdx.x * 4 + (threadIdx.x >> 6);
    const float4 v = *(const float4*)(x + (size_t)row * D + l * 4);
    float s  = v.x + v.y + v.z + v.w;
    float s2 = v.x * v.x + v.y * v.y + v.z * v.z + v.w * v.w;
    #pragma unroll
    for (int off = 32; off > 0; off >>= 1) {
        s  += __shfl_xor(s, off, 64);
        s2 += __shfl_xor(s2, off, 64);
    }
    float mu  = s * (1.0f / D);
    float var = s2 * (1.0f / D) - mu * mu;
    float rs  = rsqrtf(var + 1e-5f);
    const float4 gg = *(const float4*)(g + l * 4);
    const float4 bb = *(const float4*)(b + l * 4);
    ushort4 o;
    o.x = f2bf((v.x - mu) * rs * gg.x + bb.x);
    o.y = f2bf((v.y - mu) * rs * gg.y + bb.y);
    o.z = f2bf((v.z - mu) * rs * gg.z + bb.z);
    o.w = f2bf((v.w - mu) * rs * gg.w + bb.w);
    *(ushort4*)(out + (size_t)row * D + l * 4) = o;
}

// ------- bf16 MFMA GEMM, 64x64 tile, BK=64 dbuf (4 barriers @K=256), swizzled -------
// modes: 0 = QKV: RoPE+store bf16 for cols<512 (Q cols<256 pre-scaled), cols>=512
//            stored TRANSPOSED to vt[B][H][DH][S];  2 = bf16 store gelu(acc+bias)
__global__ __launch_bounds__(256) void gemm64b(const unsigned short* __restrict__ A,
        const unsigned short* __restrict__ Bw, void* __restrict__ outp,
        unsigned short* __restrict__ vt,
        const float* __restrict__ bias,
        const float* __restrict__ ct, const float* __restrict__ st,
        int N, int K, int mode) {
    __shared__ unsigned short As[2][64 * 64];
    __shared__ unsigned short Bs[2][64 * 64];
    int tid = threadIdx.x;
    int w = tid >> 6, l = tid & 63;
    int lm = l & 15, lg = l >> 4;
    int wm = (w >> 1) * 32, wn = (w & 1) * 32;
    int bm = blockIdx.x * 64, bn = blockIdx.y * 64;
    int r1 = tid >> 3, pc = tid & 7;
    int pcx = (pc ^ (r1 & 7)) * 8;
    const unsigned short* Ag1 = A + (size_t)(bm + r1) * K + pcx;
    const unsigned short* Ag2 = A + (size_t)(bm + 32 + r1) * K + pcx;
    const unsigned short* Bg1 = Bw + (size_t)(bn + r1) * K + pcx;
    const unsigned short* Bg2 = Bw + (size_t)(bn + 32 + r1) * K + pcx;
    const int swz = lm & 7;
    f32x4 acc[2][2] = {};

    gload16(Ag1, &As[0][w * 512]);
    gload16(Ag2, &As[0][2048 + w * 512]);
    gload16(Bg1, &Bs[0][w * 512]);
    gload16(Bg2, &Bs[0][2048 + w * 512]);
    for (int k0 = 0; k0 < K; k0 += 64) {
        int cur = (k0 >> 6) & 1;
        __syncthreads();
        if (k0 + 64 < K) {
            gload16(Ag1 + k0 + 64, &As[1 - cur][w * 512]);
            gload16(Ag2 + k0 + 64, &As[1 - cur][2048 + w * 512]);
            gload16(Bg1 + k0 + 64, &Bs[1 - cur][w * 512]);
            gload16(Bg2 + k0 + 64, &Bs[1 - cur][2048 + w * 512]);
        }
        #pragma unroll
        for (int j = 0; j < 2; ++j) {
            int ch = ((j * 4 + lg) ^ swz) * 8;
            short8 af[2], bf[2];
            #pragma unroll
            for (int i = 0; i < 2; ++i) af[i] = *(const short8*)&As[cur][(wm + i * 16 + lm) * 64 + ch];
            #pragma unroll
            for (int i = 0; i < 2; ++i) bf[i] = *(const short8*)&Bs[cur][(wn + i * 16 + lm) * 64 + ch];
            #pragma unroll
            for (int mi = 0; mi < 2; ++mi)
                #pragma unroll
                for (int ni = 0; ni < 2; ++ni)
                    acc[mi][ni] = __builtin_amdgcn_mfma_f32_16x16x32_bf16(af[mi], bf[ni], acc[mi][ni], 0, 0, 0);
        }
    }

    if (mode == 0) {
        if (bn >= 512) {
            #pragma unroll
            for (int mi = 0; mi < 2; ++mi) {
                #pragma unroll
                for (int ni = 0; ni < 2; ++ni) {
                    int ng = bn + wn + ni * 16 + lm - 512;   // h*32+dh
                    int hh = ng >> 5, dh = ng & 31;
                    int mg0 = bm + wm + mi * 16 + lg * 4;
                    int bb = mg0 >> 12, ss = mg0 & 4095;
                    ushort4 pv;
                    pv.x = f2bf(acc[mi][ni][0]); pv.y = f2bf(acc[mi][ni][1]);
                    pv.z = f2bf(acc[mi][ni][2]); pv.w = f2bf(acc[mi][ni][3]);
                    *(ushort4*)(vt + ((size_t)((bb * 8 + hh) * 32 + dh)) * S + ss) = pv;
                }
            }
        } else {
            #pragma unroll
            for (int mi = 0; mi < 2; ++mi) {
                #pragma unroll
                for (int ni = 0; ni < 2; ++ni) {
                    int ng = bn + wn + ni * 16 + lm;
                    int pi = (ng & 31) >> 1;
                    float sgn = (ng & 1) ? 1.f : -1.f;
                    float qs  = (ng < 256) ? QSCALE : 1.f;
                    #pragma unroll
                    for (int r2 = 0; r2 < 4; ++r2) {
                        int mg = bm + wm + mi * 16 + lg * 4 + r2;
                        int spos = mg & (S - 1);
                        float vv = acc[mi][ni][r2];
                        float pv = __shfl_xor(vv, 1, 64);
                        float cs = ct[spos * 16 + pi];
                        float sn = st[spos * 16 + pi];
                        float ov = (vv * cs + sgn * pv * sn) * qs;
                        ((unsigned short*)outp)[(size_t)mg * N + ng] = f2bf(ov);
                    }
                }
            }
        }
        return;
    }
    // mode 2: gelu(acc+bias), bf16 store
    #pragma unroll
    for (int mi = 0; mi < 2; ++mi) {
        #pragma unroll
        for (int ni = 0; ni < 2; ++ni) {
            int ng = bn + wn + ni * 16 + lm;
            #pragma unroll
            for (int r2 = 0; r2 < 4; ++r2) {
                int mg = bm + wm + mi * 16 + lg * 4 + r2;
                float t = acc[mi][ni][r2] + bias[ng];
                ((unsigned short*)outp)[(size_t)mg * N + ng] =
                    f2bf(0.5f * t * (1.0f + erff(t * 0.70710678118654752f)));
            }
        }
    }
}

// ------- bf16 MFMA GEMM, 32x64 tile, BK=128 dbuf: for the N=256 GEMMs -------
// modes: 1 = fp32 store acc+res; 3 = fp32 store acc+bias+res
__global__ __launch_bounds__(256) void gemm32(const unsigned short* __restrict__ A,
        const unsigned short* __restrict__ Bw, void* __restrict__ outp,
        const float* __restrict__ bias, const float* __restrict__ res,
        int N, int K, int mode) {
    __shared__ unsigned short As[2][32 * 128];
    __shared__ unsigned short Bs[2][64 * 128];
    int tid = threadIdx.x;
    int w = tid >> 6, l = tid & 63;
    int lm = l & 15, lg = l >> 4;
    int rm = (w >> 1) * 16, wn = (w & 1) * 32;
    int bm = blockIdx.x * 32, bn = blockIdx.y * 64;
    int r1 = tid >> 4, pc = tid & 15;
    int pcx = (pc ^ (r1 & 7)) * 8;
    const unsigned short* Ag1 = A + (size_t)(bm + r1) * K + pcx;
    const unsigned short* Ag2 = A + (size_t)(bm + 16 + r1) * K + pcx;
    const unsigned short* Bg1 = Bw + (size_t)(bn + r1) * K + pcx;
    const unsigned short* Bg2 = Bw + (size_t)(bn + 16 + r1) * K + pcx;
    const unsigned short* Bg3 = Bw + (size_t)(bn + 32 + r1) * K + pcx;
    const unsigned short* Bg4 = Bw + (size_t)(bn + 48 + r1) * K + pcx;
    const int swz = lm & 7;
    f32x4 acc[2] = {};

    gload16(Ag1, &As[0][w * 512]);
    gload16(Ag2, &As[0][2048 + w * 512]);
    gload16(Bg1, &Bs[0][w * 512]);
    gload16(Bg2, &Bs[0][2048 + w * 512]);
    gload16(Bg3, &Bs[0][4096 + w * 512]);
    gload16(Bg4, &Bs[0][6144 + w * 512]);
    for (int k0 = 0; k0 < K; k0 += 128) {
        int cur = (k0 >> 7) & 1;
        __syncthreads();
        if (k0 + 128 < K) {
            gload16(Ag1 + k0 + 128, &As[1 - cur][w * 512]);
            gload16(Ag2 + k0 + 128, &As[1 - cur][2048 + w * 512]);
            gload16(Bg1 + k0 + 128, &Bs[1 - cur][w * 512]);
            gload16(Bg2 + k0 + 128, &Bs[1 - cur][2048 + w * 512]);
            gload16(Bg3 + k0 + 128, &Bs[1 - cur][4096 + w * 512]);
            gload16(Bg4 + k0 + 128, &Bs[1 - cur][6144 + w * 512]);
        }
        #pragma unroll
        for (int j = 0; j < 4; ++j) {
            int ch = ((j * 4 + lg) ^ swz) * 8;
            short8 af = *(const short8*)&As[cur][(rm + lm) * 128 + ch];
            short8 bf[2];
            #pragma unroll
            for (int i = 0; i < 2; ++i) bf[i] = *(const short8*)&Bs[cur][(wn + i * 16 + lm) * 128 + ch];
            #pragma unroll
            for (int ni = 0; ni < 2; ++ni)
                acc[ni] = __builtin_amdgcn_mfma_f32_16x16x32_bf16(af, bf[ni], acc[ni], 0, 0, 0);
        }
    }

    #pragma unroll
    for (int ni = 0; ni < 2; ++ni) {
        int ng = bn + wn + ni * 16 + lm;
        #pragma unroll
        for (int r2 = 0; r2 < 4; ++r2) {
            int mg = bm + rm + lg * 4 + r2;
            float v = acc[ni][r2];
            size_t idx = (size_t)mg * N + ng;
            if (mode == 1) {
                ((float*)outp)[idx] = v + res[idx];
            } else {
                ((float*)outp)[idx] = v + bias[ng] + res[idx];
            }
        }
    }
}

// -------- MFMA flash attention: registers-only P, split-key dual groups (R14) ------
// XCD-clustered decode (verified: hbm_bytes -63%). Denominator rides the PV MFMA via
// the ones-row tile (R16 showed the register-denominator variant costs +4us: it moves
// work from the co-issued MFMA pipe onto the busier VALU pipe).
__global__ __launch_bounds__(512) void attn_kernel(const unsigned short* __restrict__ Cq,
        const unsigned short* __restrict__ vt, unsigned short* __restrict__ out) {
    __shared__ unsigned short Ks[2][2][64][32];  // [grp][buf][phys key row][dim]
    __shared__ unsigned short Vs[2][2][32][64];  // [grp][buf][dim][key]
    __shared__ unsigned short Ones[16][64];      // row 0 = 1.0bf16, rest 0
    int tid = threadIdx.x;
    int w = tid >> 6, l = tid & 63;
    int grp = w >> 2, ws = w & 3;
    int lm = l & 15, lg = l >> 4;
    int qt = blockIdx.x >> 4;                    // XCD-cluster swizzle
    int bh = blockIdx.x & 15;
    int bb = bh >> 3, h = bh & 7;
    int q0 = qt * 64 + ws * 16;

    if (tid < 256) {   // ones tile init (16x64 ushorts = 256 lanes x 4)
        unsigned short val = (tid < 16) ? (unsigned short)0x3F80 : (unsigned short)0;
        *(ushort4*)(&Ones[0][0] + tid * 4) = make_ushort4(val, val, val, val);
    }

    const short8 qf = *(const short8*)(Cq + ((size_t)(bb * S + q0 + lm)) * 768 + h * DH + lg * 8);
    int p = ws * 16 + (l >> 2);
    int krow = ((p >> 5) << 5) + (((p >> 2) & 3) << 3) + (((p >> 4) & 1) << 2) + (p & 3);
    const unsigned short* kg = Cq + ((size_t)(bb * S)) * 768 + 256 + h * 32
                               + (size_t)krow * 768 + ((l & 3) ^ ((l >> 3) & 3)) * 8;
    const unsigned short* vg = vt + ((size_t)(bh * 32 + ws * 8 + (l >> 3))) * S + ((l & 7) ^ (l >> 3)) * 8;
    const int kswz = (lm >> 1) & 3;
    const int vswz = lm & 7;

    f32x4 o0 = {0.f, 0.f, 0.f, 0.f}, o1 = {0.f, 0.f, 0.f, 0.f}, o2 = {0.f, 0.f, 0.f, 0.f};
    const f32x4 z = {0.f, 0.f, 0.f, 0.f};

    gload16(kg + (size_t)grp * 64 * 768, &Ks[grp][0][ws * 16][0]);
    gload16(vg + (size_t)grp * 64,       &Vs[grp][0][ws * 8][0]);

    #pragma unroll 2
    for (int it = 0; it < S / 128; ++it) {       // 32 iterations per group
        int cur = it & 1;
        __syncthreads();
        if (it + 1 < S / 128) {
            size_t t = (size_t)(2 * (it + 1) + grp);
            gload16(kg + t * 64 * 768, &Ks[grp][1 - cur][ws * 16][0]);
            gload16(vg + t * 64,       &Vs[grp][1 - cur][ws * 8][0]);
        }
        #pragma unroll
        for (int half = 0; half < 2; ++half) {
            short8 kf0 = *(const short8*)&Ks[grp][cur][half * 32 + lm][(lg ^ kswz) * 8];
            short8 kf1 = *(const short8*)&Ks[grp][cur][half * 32 + 16 + lm][(lg ^ kswz) * 8];
            f32x4 s0 = __builtin_amdgcn_mfma_f32_16x16x32_bf16(kf0, qf, z, 0, 0, 0);
            f32x4 s1 = __builtin_amdgcn_mfma_f32_16x16x32_bf16(kf1, qf, z, 0, 0, 0);
            unsigned u0[4], u1[4];
            #pragma unroll
            for (int i = 0; i < 4; ++i) {
                union { float f; unsigned u; } c0, c1;
                c0.f = __builtin_amdgcn_exp2f(s0[i]);
                c1.f = __builtin_amdgcn_exp2f(s1[i]);
                u0[i] = c0.u;   // truncate to bf16 (bias cancels num/denom)
                u1[i] = c1.u;
            }
            union { unsigned u[4]; short8 s; } pk;
            pk.u[0] = __builtin_amdgcn_perm(u0[1], u0[0], 0x07060302u);
            pk.u[1] = __builtin_amdgcn_perm(u0[3], u0[2], 0x07060302u);
            pk.u[2] = __builtin_amdgcn_perm(u1[1], u1[0], 0x07060302u);
            pk.u[3] = __builtin_amdgcn_perm(u1[3], u1[2], 0x07060302u);
            short8 pf = pk.s;   // B-operand fragment: keys 8lg..8lg+7, q=lm
            int vc = ((half * 4 + lg) ^ vswz) * 8;
            short8 va0 = *(const short8*)&Vs[grp][cur][lm][vc];
            short8 va1 = *(const short8*)&Vs[grp][cur][16 + lm][vc];
            short8 va2 = *(const short8*)&Ones[lm][vc];
            o0 = __builtin_amdgcn_mfma_f32_16x16x32_bf16(va0, pf, o0, 0, 0, 0);
            o1 = __builtin_amdgcn_mfma_f32_16x16x32_bf16(va1, pf, o1, 0, 0, 0);
            o2 = __builtin_amdgcn_mfma_f32_16x16x32_bf16(va2, pf, o2, 0, 0, 0);
        }
    }
    // cross-group combine via LDS aliased onto group1's dead staging buffers
    f32x4* Red0 = (f32x4*)&Ks[1][0][0][0];   // 4KB
    f32x4* Red1 = (f32x4*)&Vs[1][0][0][0];   // 4KB
    float* Den  = (float*)&Ones[0][0];       // 1KB
    __syncthreads();
    if (grp) {
        Red0[ws * 64 + l] = o0;
        Red1[ws * 64 + l] = o1;
        Den[ws * 64 + l]  = o2[0];
    }
    __syncthreads();
    if (!grp) {
        f32x4 a0 = Red0[ws * 64 + l];
        f32x4 a1 = Red1[ws * 64 + l];
        float dd = o2[0] + Den[ws * 64 + l];
        #pragma unroll
        for (int i = 0; i < 4; ++i) { o0[i] += a0[i]; o1[i] += a1[i]; }
        float lsum = __shfl(dd, lm, 64);
        float inv = 1.0f / lsum;
        ushort4 r0, r1;
        r0.x = f2bf(o0[0] * inv); r0.y = f2bf(o0[1] * inv);
        r0.z = f2bf(o0[2] * inv); r0.w = f2bf(o0[3] * inv);
        r1.x = f2bf(o1[0] * inv); r1.y = f2bf(o1[1] * inv);
        r1.z = f2bf(o1[2] * inv); r1.w = f2bf(o1[3] * inv);
        unsigned short* ob = out + ((size_t)(bb * S + q0 + lm)) * D + h * DH;
        *(ushort4*)(ob + lg * 4)      = r0;
        *(ushort4*)(ob + 16 + lg * 4) = r1;
    }
}

extern "C" void kernel_launch(void* const* d_in, const int* in_sizes, int n_in,
                              void* d_out, int out_size, void* d_ws, size_t ws_size,
                              hipStream_t stream) {
    const float* x     = (const float*)d_in[0];
    const float* Wq    = (const float*)d_in[1];
    const float* Wk    = (const float*)d_in[2];
    const float* Wv    = (const float*)d_in[3];
    const float* Wo    = (const float*)d_in[4];
    const float* ln1_g = (const float*)d_in[5];
    const float* ln1_b = (const float*)d_in[6];
    const float* ln2_g = (const float*)d_in[7];
    const float* ln2_b = (const float*)d_in[8];
    const float* W2    = (const float*)d_in[9];
    const float* b2    = (const float*)d_in[10];
    const float* W3    = (const float*)d_in[11];
    const float* b3    = (const float*)d_in[12];

    char* w8 = (char*)d_ws;
    unsigned short* wqkv = (unsigned short*)(w8);             // 196608 ush
    unsigned short* wo_b = (unsigned short*)(w8 + 393216);    // 65536
    unsigned short* w2_b = (unsigned short*)(w8 + 524288);    // 262144
    unsigned short* w3_b = (unsigned short*)(w8 + 1048576);   // 262144
    float*          ct   = (float*)(w8 + 1572864);            // 65536 f32
    float*          st   = (float*)(w8 + 1835008);            // 65536 f32
    unsigned short* xn   = (unsigned short*)(w8 + 2097152);   // 2M ush (reused as yn)
    unsigned short* Cq   = (unsigned short*)(w8 + 6291456);   // 6.29M ush (QKV out)
    unsigned short* hb   = Cq;                                // MLP hidden reuses (16MB)
    unsigned short* vtb  = (unsigned short*)(w8 + 23068672);  // 2M ush
    unsigned short* ab   = (unsigned short*)(w8 + 27262976);  // 2M ush
    float*          mlpin= (float*)(w8 + 31457280);           // 2M f32
    unsigned short* yn   = xn;

    prep<<<5376, 256, 0, stream>>>(Wq, Wk, Wv, Wo, W2, W3, wqkv, wo_b, w2_b, w3_b,
                                   ct, st, x, ln1_g, ln1_b, xn);
    gemm64b<<<dim3(128, 12), 256, 0, stream>>>(xn, wqkv, Cq, vtb, nullptr, ct, st, 768, 256, 0);
    attn_kernel<<<1024, 512, 0, stream>>>(Cq, vtb, ab);
    gemm32<<<dim3(256, 4), 256, 0, stream>>>(ab, wo_b, mlpin, nullptr, x, 256, 256, 1);
    ln_kernel<<<NTOK / 4, 256, 0, stream>>>(mlpin, ln2_g, ln2_b, yn);
    gemm64b<<<dim3(128, 16), 256, 0, stream>>>(yn, w2_b, hb, nullptr, b2, nullptr, nullptr, 1024, 256, 2);
    gemm32<<<dim3(256, 4), 256, 0, stream>>>(hb, w3_b, (float*)d_out, b3, mlpin, 256, 1024, 3);
}